// Round 7
// baseline (910.978 us; speedup 1.0000x reference)
//
#include <hip/hip_runtime.h>

#define T_DATA 200000
#define E_NO 400
#define I_NO 100
#define SUB_NO 20
#define N_BASIS 20
#define T_NO 200

typedef unsigned short u16;
typedef unsigned int u32;

// workspace: TOTAL need = 67,768 bytes only.
#define WS_K4    0          // 4000 float4 = 64000 B
#define WS_HIST2 64000      // 200 float2 = 1600 B
#define WS_LISTS 65600      // 542 int = 2168 B

__device__ __forceinline__ u16 f2bf(float f) {
    union { float f; u32 u; } v; v.f = f;
    u32 u = v.u;
    u32 lsb = (u >> 16) & 1u;
    u += 0x7fffu + lsb;            // RNE
    return (u16)(u >> 16);
}
__device__ __forceinline__ float bf2f(u16 b) {
    union { u32 u; float f; } v; v.u = ((u32)b) << 16; return v.f;
}
__device__ __forceinline__ void unp2(u32 w, float& a, float& b) {
    union { u32 u; float f; } c;
    c.u = w << 16;          a = c.f;
    c.u = w & 0xffff0000u;  b = c.f;
}
__device__ __forceinline__ float fast_tanh(float x) {
    x = fminf(fmaxf(x, -15.f), 15.f);
    float e = __expf(2.f * x);
    return 1.f - 2.f / (e + 1.f);
}
__device__ __forceinline__ float fast_sigmoid(float x) {
    x = fminf(fmaxf(x, -30.f), 30.f);
    return 1.f / (1.f + __expf(-x));
}

// ============================================================================
// Kernel 1: filters, hist kernels, assignment lists, out_filters (f32).
// One block. ws writes confined to [0, 67768).
// ============================================================================
__global__ __launch_bounds__(256) void k_setup(
    const float* __restrict__ Wns, const float* __restrict__ Tau,
    const float* __restrict__ Del, const float* __restrict__ Wsyns,
    const float* __restrict__ HwS, const float* __restrict__ HwNS,
    const float* __restrict__ Cse, const float* __restrict__ Csi,
    float4* __restrict__ k4, float2* __restrict__ hist2,
    int* __restrict__ lists, float* __restrict__ outF)
{
    __shared__ float cb[N_BASIS * T_NO];
    __shared__ int easn[E_NO], iasn[I_NO];
    __shared__ int cnt[2 * SUB_NO], cur[2 * SUB_NO];
    const int tid = threadIdx.x;
    const float PI = 3.14159265358979323846f;

    if (tid < 2 * SUB_NO) cnt[tid] = 0;
    __syncthreads();

    for (int it = tid; it < N_BASIS * T_NO; it += 256) {
        int b = it / T_NO, j = it % T_NO;
        float phi = 1.57079632679489662f * (float)b;
        float raw = 5.0f * logf((float)j + 1.0f);
        float v = 0.f;
        if (raw >= phi - PI && raw <= phi + PI) v = 0.5f * cosf(raw - phi) + 0.5f;
        cb[it] = v;
    }
    for (int j = tid; j < E_NO; j += 256) {
        int a = 0;
        for (int s = 0; s < SUB_NO; ++s)
            if (Cse[s * E_NO + j] > 0.5f) a = s;
        easn[j] = a;
        atomicAdd(&cnt[a], 1);
    }
    for (int j = tid; j < I_NO; j += 256) {
        int a = 0;
        for (int s = 0; s < SUB_NO; ++s)
            if (Csi[s * I_NO + j] > 0.5f) a = s;
        iasn[j] = a;
        atomicAdd(&cnt[SUB_NO + a], 1);
    }
    __syncthreads();
    if (tid == 0) {
        int aE = 0, aI = 0;
        for (int s = 0; s < SUB_NO; ++s) {
            lists[s] = aE;      cur[s] = aE;           aE += cnt[s];
            lists[21 + s] = aI; cur[SUB_NO + s] = aI;  aI += cnt[SUB_NO + s];
        }
        lists[20] = aE;
        lists[41] = aI;
    }
    __syncthreads();
    for (int j = tid; j < E_NO; j += 256) {
        int p = atomicAdd(&cur[easn[j]], 1);
        lists[42 + p] = j;
    }
    for (int j = tid; j < I_NO; j += 256) {
        int p = atomicAdd(&cur[SUB_NO + iasn[j]], 1);
        lists[442 + p] = j;
    }

    for (int it = tid; it < SUB_NO * T_NO; it += 256) {
        int s = it / T_NO, j = it % T_NO;
        float tau_e = Tau[s * 2 + 0]; tau_e *= tau_e;
        float tau_i = Tau[s * 2 + 1]; tau_i *= tau_i;
        float de = Del[s * 2 + 0], di = Del[s * 2 + 1];
        float we = Wns[s * 2 + 0]; we *= we;
        float wi = Wns[s * 2 + 1]; wi *= wi;
        float te = fmaxf((float)j - de, 0.f) / tau_e;
        float ti = fmaxf((float)j - di, 0.f) / tau_i;
        float eNs = te * expf(-te) * we;
        float iNs = -ti * expf(-ti) * wi;
        float eS = 0.f, iS = 0.f;
        for (int b = 0; b < N_BASIS; ++b) {
            float w0 = Wsyns[(s * N_BASIS + b) * 2 + 0];
            float w1 = Wsyns[(s * N_BASIS + b) * 2 + 1];
            float c = cb[b * T_NO + j];
            eS += w0 * w0 * c;
            iS -= w1 * w1 * c;
        }
        k4[it] = make_float4(eNs, iNs, eS, iS);
        outF[it]         = eNs;     // rows 0..19  e_kern_ns
        outF[4000 + it]  = iNs;     // rows 20..39 i_kern_ns
        outF[8000 + it]  = eS;      // rows 40..59 e_kern_s
        outF[12000 + it] = iS;      // rows 60..79 i_kern_s
    }
    for (int j = tid; j < T_NO; j += 256) {
        float hn = 0.f, hs = 0.f;
        for (int b = 0; b < N_BASIS; ++b) {
            float c = cb[b * T_NO + j];
            hn += HwNS[b] * c;
            hs += HwS[b] * c;
        }
        hist2[j] = make_float2(hn, hs);
        outF[16000 + j] = hn;       // row 80 hist_ns
        outF[16200 + j] = hs;       // row 81 hist_s
    }
}

// ============================================================================
// Kernel 2 (fused): spike-sum + hist + depthwise conv + tree + f32 outputs.
// Block = 512-t tile; thread owns 2 consecutive t. LDS ~79 KB -> 2 blocks/CU
// (gfx950 static LDS >64KB verified working in R5).
// ============================================================================
#define TT 512
#define WROW 712                     // window [t0-200, t0+512)
__global__ __launch_bounds__(256) void k_fused(
    const float* __restrict__ Se, const float* __restrict__ Si,
    const float* __restrict__ Z,
    const float4* __restrict__ k4g, const float2* __restrict__ hist2g,
    const int* __restrict__ listsg,
    const int* __restrict__ Cden,
    const float* __restrict__ WsubNS, const float* __restrict__ WsubS,
    const float* __restrict__ Vo, const float* __restrict__ ThNS,
    const float* __restrict__ ThS,
    float* __restrict__ outV, float* __restrict__ outZ)
{
    __shared__ __align__(16) u16 sE[SUB_NO * WROW];   // 28480 B (later syn_ns)
    __shared__ __align__(16) u16 sI[SUB_NO * WROW];   // 28480 B (later syn_s)
    __shared__ __align__(16) float scr[3200];         // 12800 B staging scratch
    __shared__ __align__(16) float4 k4l[T_NO];        // 3200 B
    __shared__ float2 hl[T_NO];                       // 1600 B
    __shared__ float AS[SUB_NO][SUB_NO], AN[SUB_NO][SUB_NO];  // 3200 B
    __shared__ float ths[SUB_NO], thn[SUB_NO];
    __shared__ int leo[21], lio[21];
    __shared__ u16 lei[E_NO], lii[I_NO];
    __shared__ float wn20s, vos;
    const int tid = threadIdx.x;
    const int t0 = blockIdx.x * TT;
    const int W0 = t0 - 200;

    // ---- stage small params / lists ----
    if (tid < 21) { leo[tid] = listsg[tid]; lio[tid] = listsg[21 + tid]; }
    for (int k = tid; k < E_NO; k += 256) lei[k] = (u16)listsg[42 + k];
    for (int k = tid; k < I_NO; k += 256) lii[k] = (u16)listsg[442 + k];
    if (tid < T_NO) hl[tid] = hist2g[tid];
    for (int k = tid; k < SUB_NO * SUB_NO; k += 256) {
        int idx = k / SUB_NO, c = k - idx * SUB_NO;
        float m = (float)Cden[k];
        float wsv = WsubS[c];
        float wnv = WsubNS[c];
        AS[idx][c] = m * wsv * wsv;
        AN[idx][c] = m * wnv * wnv;
    }
    if (tid < SUB_NO) { ths[tid] = ThS[tid]; thn[tid] = ThNS[tid]; }
    if (tid == 0) {
        float w = WsubNS[0];
        wn20s = w * w;
        vos = Vo[0];
    }

    // ================= E spike staging: 89 tiles x 8 rows =================
    float4 pe[4];
    {
#pragma unroll
        for (int q = 0; q < 4; ++q) {
            int k = tid + q * 256;
            float4 v = make_float4(0.f, 0.f, 0.f, 0.f);
            if (k < 800) {
                int r = k / 100, c = k - r * 100;
                int t = W0 + r;
                if (t >= 0 && t < T_DATA) v = ((const float4*)Se)[t * 100 + c];
            }
            pe[q] = v;
        }
        __syncthreads();                 // params/lists visible
#pragma unroll
        for (int q = 0; q < 4; ++q) {
            int k = tid + q * 256;
            if (k < 800) ((float4*)scr)[k] = pe[q];
        }
        __syncthreads();
    }
#pragma unroll 1
    for (int it = 1; it < 89; ++it) {
#pragma unroll
        for (int q = 0; q < 4; ++q) {
            int k = tid + q * 256;
            float4 v = make_float4(0.f, 0.f, 0.f, 0.f);
            if (k < 800) {
                int r = k / 100, c = k - r * 100;
                int t = W0 + it * 8 + r;
                if (t >= 0 && t < T_DATA) v = ((const float4*)Se)[t * 100 + c];
            }
            pe[q] = v;
        }
        if (tid < 160) {
            int r = tid / 20, s = tid - (tid / 20) * 20;
            float a = 0.f;
            for (int k = leo[s]; k < leo[s + 1]; ++k) a += scr[r * 400 + lei[k]];
            sE[s * WROW + (it - 1) * 8 + r] = f2bf(a);
        }
        __syncthreads();
#pragma unroll
        for (int q = 0; q < 4; ++q) {
            int k = tid + q * 256;
            if (k < 800) ((float4*)scr)[k] = pe[q];
        }
        __syncthreads();
    }
    if (tid < 160) {                     // final tile (it=88)
        int r = tid / 20, s = tid - (tid / 20) * 20;
        float a = 0.f;
        for (int k = leo[s]; k < leo[s + 1]; ++k) a += scr[r * 400 + lei[k]];
        sE[s * WROW + 88 * 8 + r] = f2bf(a);
    }
    __syncthreads();

    // ================= I spike staging: 45 tiles x 16 rows =================
    float4 pi2[2];
    {
#pragma unroll
        for (int q = 0; q < 2; ++q) {
            int k = tid + q * 256;
            float4 v = make_float4(0.f, 0.f, 0.f, 0.f);
            if (k < 400) {
                int r = k / 25, c = k - r * 25;
                int t = W0 + r;
                if (t >= 0 && t < T_DATA) v = ((const float4*)Si)[t * 25 + c];
            }
            pi2[q] = v;
        }
#pragma unroll
        for (int q = 0; q < 2; ++q) {
            int k = tid + q * 256;
            if (k < 400) {
                int r = k / 25, c = k - r * 25;
                ((float4*)scr)[r * 26 + c] = pi2[q];
            }
        }
        __syncthreads();
    }
#pragma unroll 1
    for (int it = 1; it < 45; ++it) {
#pragma unroll
        for (int q = 0; q < 2; ++q) {
            int k = tid + q * 256;
            float4 v = make_float4(0.f, 0.f, 0.f, 0.f);
            if (k < 400) {
                int r = k / 25, c = k - r * 25;
                int t = W0 + it * 16 + r;
                if (t >= 0 && t < T_DATA) v = ((const float4*)Si)[t * 25 + c];
            }
            pi2[q] = v;
        }
        for (int p = tid; p < 320; p += 256) {
            int r = p / 20, s = p - (p / 20) * 20;
            float a = 0.f;
            for (int k = lio[s]; k < lio[s + 1]; ++k) a += scr[r * 104 + lii[k]];
            int c = (it - 1) * 16 + r;
            if (c < WROW) sI[s * WROW + c] = f2bf(a);
        }
        __syncthreads();
#pragma unroll
        for (int q = 0; q < 2; ++q) {
            int k = tid + q * 256;
            if (k < 400) {
                int r = k / 25, c = k - r * 25;
                ((float4*)scr)[r * 26 + c] = pi2[q];
            }
        }
        __syncthreads();
    }
    for (int p = tid; p < 320; p += 256) {   // final tile (it=44)
        int r = p / 20, s = p - (p / 20) * 20;
        float a = 0.f;
        for (int k = lio[s]; k < lio[s + 1]; ++k) a += scr[r * 104 + lii[k]];
        int c = 44 * 16 + r;
        if (c < WROW) sI[s * WROW + c] = f2bf(a);
    }
    __syncthreads();

    // ================= Z window + per-thread history filters =================
    if (tid < 178) {
        int t = W0 + tid * 4;
        float4 v;
        if (t >= 0 && t + 3 < T_DATA) {
            v = ((const float4*)Z)[t >> 2];
        } else {
            float x0 = (t + 0 >= 0 && t + 0 < T_DATA) ? Z[t + 0] : 0.f;
            float x1 = (t + 1 >= 0 && t + 1 < T_DATA) ? Z[t + 1] : 0.f;
            float x2 = (t + 2 >= 0 && t + 2 < T_DATA) ? Z[t + 2] : 0.f;
            float x3 = (t + 3 >= 0 && t + 3 < T_DATA) ? Z[t + 3] : 0.f;
            v = make_float4(x0, x1, x2, x3);
        }
        ((float4*)scr)[tid] = v;
    }
    __syncthreads();
    float hn0 = 0.f, hs0 = 0.f, hn1 = 0.f, hs1 = 0.f;
    {
        const int i0 = tid * 2;
        for (int j = 0; j < T_NO; ++j) {
            float2 h = hl[j];
            float za = scr[i0 + 199 - j];    // Z[(t0+i0)-1-j]
            float zb = scr[i0 + 200 - j];    // Z[(t0+i0+1)-1-j]
            hn0 = fmaf(h.x, za, hn0); hs0 = fmaf(h.y, za, hs0);
            hn1 = fmaf(h.x, zb, hn1); hs1 = fmaf(h.y, zb, hs1);
        }
    }
    __syncthreads();

    // ================= per-subunit conv, write-back in place =================
#pragma unroll 1
    for (int s = 0; s < SUB_NO; ++s) {
        if (tid < T_NO) k4l[tid] = k4g[s * T_NO + tid];
        __syncthreads();

        float aN[2] = {0.f, 0.f}, aS2[2] = {0.f, 0.f};
        const u16* rowE = sE + s * WROW;
        const u16* rowI = sI + s * WROW;
#pragma unroll 1
        for (int jj = 0; jj <= 192; jj += 8) {
            const int base = tid * 2 + 192 - jj;
            float xe[10], xi[10];
            {
                const u16* p = rowE + base;
                u32 a0 = *(const u32*)(p + 0);
                u32 a1 = *(const u32*)(p + 2);
                u32 a2 = *(const u32*)(p + 4);
                u32 a3 = *(const u32*)(p + 6);
                u32 a4 = *(const u32*)(p + 8);
                unp2(a0, xe[0], xe[1]); unp2(a1, xe[2], xe[3]);
                unp2(a2, xe[4], xe[5]); unp2(a3, xe[6], xe[7]);
                unp2(a4, xe[8], xe[9]);
            }
            {
                const u16* p = rowI + base;
                u32 a0 = *(const u32*)(p + 0);
                u32 a1 = *(const u32*)(p + 2);
                u32 a2 = *(const u32*)(p + 4);
                u32 a3 = *(const u32*)(p + 6);
                u32 a4 = *(const u32*)(p + 8);
                unp2(a0, xi[0], xi[1]); unp2(a1, xi[2], xi[3]);
                unp2(a2, xi[4], xi[5]); unp2(a3, xi[6], xi[7]);
                unp2(a4, xi[8], xi[9]);
            }
#pragma unroll
            for (int k = 0; k < 8; ++k) {
                float4 kk = k4l[jj + k];
#pragma unroll
                for (int m = 0; m < 2; ++m) {
                    float e = xe[m + 8 - k];
                    float ii = xi[m + 8 - k];
                    aN[m] = fmaf(e, kk.x, fmaf(ii, kk.y, aN[m]));
                    aS2[m] = fmaf(e, kk.z, fmaf(ii, kk.w, aS2[m]));
                }
            }
        }
        __syncthreads();
        u16* wbN = sE + s * WROW + tid * 2;
        u16* wbS = sI + s * WROW + tid * 2;
        wbN[0] = f2bf(aN[0]); wbN[1] = f2bf(aN[1]);
        wbS[0] = f2bf(aS2[0]); wbS[1] = f2bf(aS2[1]);
    }
    __syncthreads();

    // ================= tree recursion + f32 outputs, 2 t per thread ==========
#pragma unroll 1
    for (int m = 0; m < 2; ++m) {
        const int i = tid * 2 + m;
        const int t = t0 + i;
        const float hfn = (m == 0) ? hn0 : hn1;
        const float hfs = (m == 0) ? hs0 : hs1;

        float vs[SUB_NO], vn[SUB_NO];
#pragma unroll
        for (int c = 0; c < SUB_NO; ++c) { vs[c] = 0.f; vn[c] = 0.f; }
#pragma unroll
        for (int idx = SUB_NO - 1; idx >= 1; --idx) {
            float cs = 0.f, cn = 0.f;
#pragma unroll
            for (int c = 0; c < SUB_NO; ++c) {
                cs = fmaf(AS[idx][c], vs[c], cs);
                cn = fmaf(AN[idx][c], vn[c], cn);
            }
            float synS_v = bf2f(sI[idx * WROW + i]);
            float synN_v = bf2f(sE[idx * WROW + i]);
            vs[idx] = fast_tanh(synS_v + cs + ths[idx]);
            vn[idx] = fast_tanh(synN_v + cn + thn[idx]);
        }
        float cs0 = 0.f, cn0 = 0.f;
#pragma unroll
        for (int c = 0; c < SUB_NO; ++c) {
            cs0 = fmaf(AS[0][c], vs[c], cs0);
            cn0 = fmaf(AN[0][c], vn[c], cn0);
        }
        float s0  = fast_sigmoid(hfs + bf2f(sI[i]) + cs0 + ths[0]);
        float ns0 = fast_tanh(hfn + bf2f(sE[i]) + cn0 + thn[0]);

        if (t < T_DATA) {
            outV[t] = ns0 * wn20s + vos;   // f32 store
            outZ[t] = s0;                  // f32 store
        }
    }
}

// ============================================================================
extern "C" void kernel_launch(void* const* d_in, const int* in_sizes, int n_in,
                              void* d_out, int out_size, void* d_ws, size_t ws_size,
                              hipStream_t stream)
{
    const float* Se    = (const float*)d_in[0];
    const float* Si    = (const float*)d_in[1];
    const float* Z     = (const float*)d_in[2];
    const int*   Cden  = (const int*)d_in[3];
    const float* Wns   = (const float*)d_in[6];
    const float* Tau   = (const float*)d_in[7];
    const float* Del   = (const float*)d_in[8];
    const float* Wsyns = (const float*)d_in[9];
    const float* WsubNS= (const float*)d_in[10];
    const float* WsubS = (const float*)d_in[11];
    const float* Vo    = (const float*)d_in[12];
    const float* ThNS  = (const float*)d_in[13];
    const float* ThS   = (const float*)d_in[14];
    const float* HwS   = (const float*)d_in[15];
    const float* HwNS  = (const float*)d_in[16];
    const float* Cse   = (const float*)d_in[4];
    const float* Csi   = (const float*)d_in[5];

    char* ws = (char*)d_ws;
    float4* k4    = (float4*)(ws + WS_K4);
    float2* hist2 = (float2*)(ws + WS_HIST2);
    int*    lists = (int*)(ws + WS_LISTS);

    // Output: FLOAT32, return order (final_V, final_Z, out_filters).
    float* outV = (float*)d_out;           // [0, 200000)
    float* outZ = outV + T_DATA;           // [200000, 400000)
    float* outF = outV + 2 * T_DATA;       // [400000, 416400)

    k_setup<<<1, 256, 0, stream>>>(Wns, Tau, Del, Wsyns, HwS, HwNS, Cse, Csi,
                                   k4, hist2, lists, outF);
    k_fused<<<(T_DATA + TT - 1) / TT, 256, 0, stream>>>(
        Se, Si, Z, k4, hist2, lists, Cden, WsubNS, WsubS, Vo, ThNS, ThS,
        outV, outZ);
}

// Round 8
// 762.579 us; speedup vs baseline: 1.1946x; 1.1946x over previous
//
#include <hip/hip_runtime.h>

#define T_DATA 200000
#define E_NO 400
#define I_NO 100
#define SUB_NO 20
#define N_BASIS 20
#define T_NO 200

typedef unsigned short u16;
typedef unsigned int u32;

// workspace: 67,768 bytes total
#define WS_K4    0          // 4000 float4
#define WS_HIST2 64000      // 200 float2
#define WS_LISTS 65600      // 542 int

__device__ __forceinline__ u16 f2bf(float f) {
    union { float f; u32 u; } v; v.f = f;
    u32 u = v.u;
    u32 lsb = (u >> 16) & 1u;
    u += 0x7fffu + lsb;            // RNE
    return (u16)(u >> 16);
}
__device__ __forceinline__ float bf2f(u16 b) {
    union { u32 u; float f; } v; v.u = ((u32)b) << 16; return v.f;
}
__device__ __forceinline__ void unpack8(uint4 u, float* x) {
    union { u32 u; float f; } c;
    c.u = u.x << 16;          x[0] = c.f;
    c.u = u.x & 0xffff0000u;  x[1] = c.f;
    c.u = u.y << 16;          x[2] = c.f;
    c.u = u.y & 0xffff0000u;  x[3] = c.f;
    c.u = u.z << 16;          x[4] = c.f;
    c.u = u.z & 0xffff0000u;  x[5] = c.f;
    c.u = u.w << 16;          x[6] = c.f;
    c.u = u.w & 0xffff0000u;  x[7] = c.f;
}
__device__ __forceinline__ float fast_tanh(float x) {
    x = fminf(fmaxf(x, -15.f), 15.f);
    float e = __expf(2.f * x);
    return 1.f - 2.f / (e + 1.f);
}
__device__ __forceinline__ float fast_sigmoid(float x) {
    x = fminf(fmaxf(x, -30.f), 30.f);
    return 1.f / (1.f + __expf(-x));
}

// ============================================================================
// k_lists: synapse->subunit assignment lists. One block (tiny).
// ============================================================================
__global__ __launch_bounds__(256) void k_lists(
    const float* __restrict__ Cse, const float* __restrict__ Csi,
    int* __restrict__ lists)
{
    __shared__ int easn[E_NO], iasn[I_NO];
    __shared__ int cnt[2 * SUB_NO], cur[2 * SUB_NO];
    const int tid = threadIdx.x;
    if (tid < 2 * SUB_NO) cnt[tid] = 0;
    __syncthreads();
    for (int j = tid; j < E_NO; j += 256) {
        int a = 0;
        for (int s = 0; s < SUB_NO; ++s)
            if (Cse[s * E_NO + j] > 0.5f) a = s;
        easn[j] = a;
        atomicAdd(&cnt[a], 1);
    }
    for (int j = tid; j < I_NO; j += 256) {
        int a = 0;
        for (int s = 0; s < SUB_NO; ++s)
            if (Csi[s * I_NO + j] > 0.5f) a = s;
        iasn[j] = a;
        atomicAdd(&cnt[SUB_NO + a], 1);
    }
    __syncthreads();
    if (tid == 0) {
        int aE = 0, aI = 0;
        for (int s = 0; s < SUB_NO; ++s) {
            lists[s] = aE;      cur[s] = aE;           aE += cnt[s];
            lists[21 + s] = aI; cur[SUB_NO + s] = aI;  aI += cnt[SUB_NO + s];
        }
        lists[20] = aE;
        lists[41] = aI;
    }
    __syncthreads();
    for (int j = tid; j < E_NO; j += 256) {
        int p = atomicAdd(&cur[easn[j]], 1);
        lists[42 + p] = j;
    }
    for (int j = tid; j < I_NO; j += 256) {
        int p = atomicAdd(&cur[SUB_NO + iasn[j]], 1);
        lists[442 + p] = j;
    }
}

// ============================================================================
// k_filters: 21 blocks. Blocks 0..19: per-subunit kernels + outF rows.
// Block 20: history kernels + hist2 + outF rows 80/81.
// ============================================================================
__global__ __launch_bounds__(256) void k_filters(
    const float* __restrict__ Wns, const float* __restrict__ Tau,
    const float* __restrict__ Del, const float* __restrict__ Wsyns,
    const float* __restrict__ HwS, const float* __restrict__ HwNS,
    float4* __restrict__ k4, float2* __restrict__ hist2,
    float* __restrict__ outF)
{
    __shared__ float cb[N_BASIS * T_NO];
    const int tid = threadIdx.x;
    const int b = blockIdx.x;
    const float PI = 3.14159265358979323846f;

    for (int it = tid; it < N_BASIS * T_NO; it += 256) {
        int bb = it / T_NO, j = it - bb * T_NO;
        float phi = 1.57079632679489662f * (float)bb;
        float raw = 5.0f * logf((float)j + 1.0f);
        float v = 0.f;
        if (raw >= phi - PI && raw <= phi + PI) v = 0.5f * cosf(raw - phi) + 0.5f;
        cb[it] = v;
    }
    __syncthreads();

    if (b < 20) {
        const int s = b;
        if (tid < T_NO) {
            const int j = tid;
            float tau_e = Tau[s * 2 + 0]; tau_e *= tau_e;
            float tau_i = Tau[s * 2 + 1]; tau_i *= tau_i;
            float de = Del[s * 2 + 0], di = Del[s * 2 + 1];
            float we = Wns[s * 2 + 0]; we *= we;
            float wi = Wns[s * 2 + 1]; wi *= wi;
            float te = fmaxf((float)j - de, 0.f) / tau_e;
            float ti = fmaxf((float)j - di, 0.f) / tau_i;
            float eNs = te * expf(-te) * we;
            float iNs = -ti * expf(-ti) * wi;
            float eS = 0.f, iS = 0.f;
            for (int bb = 0; bb < N_BASIS; ++bb) {
                float w0 = Wsyns[(s * N_BASIS + bb) * 2 + 0];
                float w1 = Wsyns[(s * N_BASIS + bb) * 2 + 1];
                float c = cb[bb * T_NO + j];
                eS += w0 * w0 * c;
                iS -= w1 * w1 * c;
            }
            int it = s * T_NO + j;
            k4[it] = make_float4(eNs, iNs, eS, iS);
            outF[it]         = eNs;
            outF[4000 + it]  = iNs;
            outF[8000 + it]  = eS;
            outF[12000 + it] = iS;
        }
    } else {
        if (tid < T_NO) {
            const int j = tid;
            float hn = 0.f, hs = 0.f;
            for (int bb = 0; bb < N_BASIS; ++bb) {
                float c = cb[bb * T_NO + j];
                hn += HwNS[bb] * c;
                hs += HwS[bb] * c;
            }
            hist2[j] = make_float2(hn, hs);
            outF[16000 + j] = hn;
            outF[16200 + j] = hs;
        }
    }
}

// ============================================================================
// k_fused: spike-sum + hist + depthwise conv + tree + f32 outputs.
// Block = 512-t tile, 256 threads. LDS 77.6 KB -> 2 blocks/CU.
//  - staging: combined E+I 8-row tiles, 89 iters, 320 gather tasks
//  - conv: 5 sweeps x 4 subunits (wave-uniform s), M=8 outputs/thread,
//    2x ds_read_b128 per operand, 256 FMA per jj-block
// ============================================================================
#define TT 512
#define WROW 712                     // [t0-200, t0+512)
__global__ __launch_bounds__(256) void k_fused(
    const float* __restrict__ Se, const float* __restrict__ Si,
    const float* __restrict__ Z,
    const float4* __restrict__ k4g, const float2* __restrict__ hist2g,
    const int* __restrict__ listsg,
    const int* __restrict__ Cden,
    const float* __restrict__ WsubNS, const float* __restrict__ WsubS,
    const float* __restrict__ Vo, const float* __restrict__ ThNS,
    const float* __restrict__ ThS,
    float* __restrict__ outV, float* __restrict__ outZ)
{
    __shared__ __align__(16) u16 sE[SUB_NO * WROW];     // 28480 B
    __shared__ __align__(16) u16 sI[SUB_NO * WROW];     // 28480 B
    __shared__ __align__(16) float scr[4032];           // 16128 B multi-use
    __shared__ float AS[SUB_NO][SUB_NO], AN[SUB_NO][SUB_NO];  // 3200 B
    __shared__ float ths[SUB_NO], thn[SUB_NO];
    __shared__ int leo[21], lio[21];
    __shared__ u16 lei[E_NO], lii[I_NO];
    __shared__ float wn20s, vos;
    const int tid = threadIdx.x;
    const int t0 = blockIdx.x * TT;
    const int W0 = t0 - 200;

    // ---- init: small params / lists ----
    if (tid < 21) { leo[tid] = listsg[tid]; lio[tid] = listsg[21 + tid]; }
    for (int k = tid; k < E_NO; k += 256) lei[k] = (u16)listsg[42 + k];
    for (int k = tid; k < I_NO; k += 256) lii[k] = (u16)listsg[442 + k];
    for (int k = tid; k < SUB_NO * SUB_NO; k += 256) {
        int idx = k / SUB_NO, c = k - idx * SUB_NO;
        float m = (float)Cden[k];
        float wsv = WsubS[c];
        float wnv = WsubNS[c];
        AS[idx][c] = m * wsv * wsv;
        AN[idx][c] = m * wnv * wnv;
    }
    if (tid < SUB_NO) { ths[tid] = ThS[tid]; thn[tid] = ThNS[tid]; }
    if (tid == 0) {
        float w = WsubNS[0];
        wn20s = w * w;
        vos = Vo[0];
    }

    // ================= staging: combined E+I, 89 tiles x 8 rows =============
    const float4* Se4 = (const float4*)Se;
    const float4* Si4 = (const float4*)Si;
    float4* scr4 = (float4*)scr;
    float4 pre[4];

#define LOAD_TILE(IT)                                                        \
    {                                                                        \
        _Pragma("unroll")                                                    \
        for (int q = 0; q < 4; ++q) {                                        \
            int k = tid + q * 256;                                           \
            float4 v = make_float4(0.f, 0.f, 0.f, 0.f);                      \
            if (k < 800) {                                                   \
                int r = k / 100, c = k - r * 100;                            \
                int t = W0 + (IT) * 8 + r;                                   \
                if (t >= 0 && t < T_DATA) v = Se4[t * 100 + c];              \
            } else if (k < 1000) {                                           \
                int kk = k - 800;                                            \
                int r = kk / 25, c = kk - r * 25;                            \
                int t = W0 + (IT) * 8 + r;                                   \
                if (t >= 0 && t < T_DATA) v = Si4[t * 25 + c];               \
            }                                                                \
            pre[q] = v;                                                      \
        }                                                                    \
    }

#define STORE_TILE()                                                         \
    {                                                                        \
        _Pragma("unroll")                                                    \
        for (int q = 0; q < 4; ++q) {                                        \
            int k = tid + q * 256;                                           \
            if (k < 800) {                                                   \
                scr4[k] = pre[q];                                            \
            } else if (k < 1000) {                                           \
                int kk = k - 800;                                            \
                int r = kk / 25, c = kk - r * 25;                            \
                scr4[800 + r * 26 + c] = pre[q];                             \
            }                                                                \
        }                                                                    \
    }

#define GATHER(IT)                                                           \
    {                                                                        \
        for (int task = tid; task < 320; task += 256) {                      \
            if (task < 160) {                                                \
                int r = task / 20, s = task - r * 20;                        \
                int k0 = leo[s], k1 = leo[s + 1];                            \
                const int bb = r * 400;                                      \
                float a0 = 0.f, a1 = 0.f, a2 = 0.f, a3 = 0.f;                \
                int k = k0;                                                  \
                for (; k + 4 <= k1; k += 4) {                                \
                    a0 += scr[bb + lei[k]];                                  \
                    a1 += scr[bb + lei[k + 1]];                              \
                    a2 += scr[bb + lei[k + 2]];                              \
                    a3 += scr[bb + lei[k + 3]];                              \
                }                                                            \
                for (; k < k1; ++k) a0 += scr[bb + lei[k]];                  \
                sE[s * WROW + (IT) * 8 + r] = f2bf((a0 + a1) + (a2 + a3));   \
            } else {                                                         \
                int tk = task - 160;                                         \
                int r = tk / 20, s = tk - r * 20;                            \
                int k0 = lio[s], k1 = lio[s + 1];                            \
                const int bb = 3200 + r * 104;                               \
                float a0 = 0.f;                                              \
                for (int k = k0; k < k1; ++k) a0 += scr[bb + lii[k]];        \
                sI[s * WROW + (IT) * 8 + r] = f2bf(a0);                      \
            }                                                                \
        }                                                                    \
    }

    LOAD_TILE(0);
    STORE_TILE();
    __syncthreads();
#pragma unroll 1
    for (int it = 1; it < 89; ++it) {
        LOAD_TILE(it);
        GATHER(it - 1);
        __syncthreads();
        STORE_TILE();
        __syncthreads();
    }
    GATHER(88);
    __syncthreads();

    // ================= hist: Z window + per-thread filters ==================
    for (int k = tid; k < WROW; k += 256) {
        int t = W0 + k;
        scr[k] = (t >= 0 && t < T_DATA) ? Z[t] : 0.f;
    }
    {
        float2* hl = (float2*)(scr + WROW);
        for (int k = tid; k < T_NO; k += 256) hl[k] = hist2g[k];
    }
    __syncthreads();
    float hn0 = 0.f, hs0 = 0.f, hn1 = 0.f, hs1 = 0.f;
    {
        const float2* hl = (const float2*)(scr + WROW);
        const int i0 = tid * 2;
        for (int j = 0; j < T_NO; ++j) {
            float2 h = hl[j];
            float za = scr[i0 + 199 - j];
            float zb = scr[i0 + 200 - j];
            hn0 = fmaf(h.x, za, hn0); hs0 = fmaf(h.y, za, hs0);
            hn1 = fmaf(h.x, zb, hn1); hs1 = fmaf(h.y, zb, hs1);
        }
    }
    __syncthreads();    // scr reads done; conv will overlay with k4 chunks

    // ================= conv: 5 sweeps x 4 subunits, M=8/thread ==============
    const int wv = tid >> 6;        // subunit within group (wave-uniform)
    const int slot = tid & 63;
    const int bT = slot * 8;        // local output base
    float4* k4c = (float4*)scr;     // 800 float4 per sweep

#pragma unroll 1
    for (int g = 0; g < 5; ++g) {
        for (int q = tid; q < 800; q += 256) {
            int su = q / 200, j = q - su * 200;
            k4c[q] = k4g[(g * 4 + su) * T_NO + j];
        }
        __syncthreads();

        const int s = g * 4 + wv;
        const u16* rowE = sE + s * WROW;
        const u16* rowI = sI + s * WROW;
        float aN[8], aS2[8];
#pragma unroll
        for (int m = 0; m < 8; ++m) { aN[m] = 0.f; aS2[m] = 0.f; }

#pragma unroll 1
        for (int jj = 0; jj <= 192; jj += 8) {
            const int p = bT + 192 - jj;         // multiple of 8 -> 16B aligned
            float xe[16], xi[16];
            uint4 eA = *(const uint4*)(rowE + p);
            uint4 eB = *(const uint4*)(rowE + p + 8);
            uint4 iA = *(const uint4*)(rowI + p);
            uint4 iB = *(const uint4*)(rowI + p + 8);
            unpack8(eA, xe); unpack8(eB, xe + 8);
            unpack8(iA, xi); unpack8(iB, xi + 8);
#pragma unroll
            for (int k = 0; k < 8; ++k) {
                float4 kk = k4c[wv * 200 + jj + k];   // broadcast
#pragma unroll
                for (int m = 0; m < 8; ++m) {
                    float e = xe[m + 8 - k];
                    float ii = xi[m + 8 - k];
                    aN[m]  = fmaf(e, kk.x, fmaf(ii, kk.y, aN[m]));
                    aS2[m] = fmaf(e, kk.z, fmaf(ii, kk.w, aS2[m]));
                }
            }
        }
        __syncthreads();                 // all reads of rows g*4..g*4+3 done
        // writeback 8 outputs per array as one b128 store each
        {
            u32 w0 = (u32)f2bf(aN[0]) | ((u32)f2bf(aN[1]) << 16);
            u32 w1 = (u32)f2bf(aN[2]) | ((u32)f2bf(aN[3]) << 16);
            u32 w2 = (u32)f2bf(aN[4]) | ((u32)f2bf(aN[5]) << 16);
            u32 w3 = (u32)f2bf(aN[6]) | ((u32)f2bf(aN[7]) << 16);
            *(uint4*)(sE + s * WROW + bT) = make_uint4(w0, w1, w2, w3);
            u32 v0 = (u32)f2bf(aS2[0]) | ((u32)f2bf(aS2[1]) << 16);
            u32 v1 = (u32)f2bf(aS2[2]) | ((u32)f2bf(aS2[3]) << 16);
            u32 v2 = (u32)f2bf(aS2[4]) | ((u32)f2bf(aS2[5]) << 16);
            u32 v3 = (u32)f2bf(aS2[6]) | ((u32)f2bf(aS2[7]) << 16);
            *(uint4*)(sI + s * WROW + bT) = make_uint4(v0, v1, v2, v3);
        }
        // no barrier needed: next sweep reads disjoint rows; k4c store is
        // fenced by next sweep's own __syncthreads after chunk load... but
        // chunk load writes scr while this sweep's k4c reads are done (they
        // precede the pre-writeback barrier). Writeback vs next chunk load:
        // disjoint regions. Safe.
    }
    __syncthreads();                     // writebacks visible for tree

    // ================= tree recursion + f32 outputs, 2 t per thread =========
#pragma unroll 1
    for (int m = 0; m < 2; ++m) {
        const int i = tid * 2 + m;
        const int t = t0 + i;
        const float hfn = (m == 0) ? hn0 : hn1;
        const float hfs = (m == 0) ? hs0 : hs1;

        float vs[SUB_NO], vn[SUB_NO];
#pragma unroll
        for (int c = 0; c < SUB_NO; ++c) { vs[c] = 0.f; vn[c] = 0.f; }
#pragma unroll
        for (int idx = SUB_NO - 1; idx >= 1; --idx) {
            float cs = 0.f, cn = 0.f;
#pragma unroll
            for (int c = 0; c < SUB_NO; ++c) {
                cs = fmaf(AS[idx][c], vs[c], cs);
                cn = fmaf(AN[idx][c], vn[c], cn);
            }
            float synS_v = bf2f(sI[idx * WROW + i]);
            float synN_v = bf2f(sE[idx * WROW + i]);
            vs[idx] = fast_tanh(synS_v + cs + ths[idx]);
            vn[idx] = fast_tanh(synN_v + cn + thn[idx]);
        }
        float cs0 = 0.f, cn0 = 0.f;
#pragma unroll
        for (int c = 0; c < SUB_NO; ++c) {
            cs0 = fmaf(AS[0][c], vs[c], cs0);
            cn0 = fmaf(AN[0][c], vn[c], cn0);
        }
        float s0  = fast_sigmoid(hfs + bf2f(sI[i]) + cs0 + ths[0]);
        float ns0 = fast_tanh(hfn + bf2f(sE[i]) + cn0 + thn[0]);

        if (t < T_DATA) {
            outV[t] = ns0 * wn20s + vos;
            outZ[t] = s0;
        }
    }
}

// ============================================================================
extern "C" void kernel_launch(void* const* d_in, const int* in_sizes, int n_in,
                              void* d_out, int out_size, void* d_ws, size_t ws_size,
                              hipStream_t stream)
{
    const float* Se    = (const float*)d_in[0];
    const float* Si    = (const float*)d_in[1];
    const float* Z     = (const float*)d_in[2];
    const int*   Cden  = (const int*)d_in[3];
    const float* Cse   = (const float*)d_in[4];
    const float* Csi   = (const float*)d_in[5];
    const float* Wns   = (const float*)d_in[6];
    const float* Tau   = (const float*)d_in[7];
    const float* Del   = (const float*)d_in[8];
    const float* Wsyns = (const float*)d_in[9];
    const float* WsubNS= (const float*)d_in[10];
    const float* WsubS = (const float*)d_in[11];
    const float* Vo    = (const float*)d_in[12];
    const float* ThNS  = (const float*)d_in[13];
    const float* ThS   = (const float*)d_in[14];
    const float* HwS   = (const float*)d_in[15];
    const float* HwNS  = (const float*)d_in[16];

    char* ws = (char*)d_ws;
    float4* k4    = (float4*)(ws + WS_K4);
    float2* hist2 = (float2*)(ws + WS_HIST2);
    int*    lists = (int*)(ws + WS_LISTS);

    // Output: float32, (final_V, final_Z, out_filters)
    float* outV = (float*)d_out;
    float* outZ = outV + T_DATA;
    float* outF = outV + 2 * T_DATA;

    k_lists<<<1, 256, 0, stream>>>(Cse, Csi, lists);
    k_filters<<<21, 256, 0, stream>>>(Wns, Tau, Del, Wsyns, HwS, HwNS,
                                      k4, hist2, outF);
    k_fused<<<(T_DATA + TT - 1) / TT, 256, 0, stream>>>(
        Se, Si, Z, k4, hist2, lists, Cden, WsubNS, WsubS, Vo, ThNS, ThS,
        outV, outZ);
}

// Round 9
// 659.568 us; speedup vs baseline: 1.3812x; 1.1562x over previous
//
#include <hip/hip_runtime.h>

#define T_DATA 200000
#define E_NO 400
#define I_NO 100
#define SUB_NO 20
#define N_BASIS 20
#define T_NO 200

typedef unsigned short u16;
typedef unsigned int u32;

// ---- workspace layout ----
// small (always used):
#define WS_K4    0          // 4000 float4 = 64000
#define WS_HIST2 64000      // 200 float2
#define WS_LISTS 65600      // 542 int -> end 67768
// big path (only if ws_size >= WS_NEED):
#define WS_SYNE  131072                  // 20*200000 u16 = 8e6
#define WS_SYNI  (WS_SYNE + 8000000)
#define WS_SNS   (WS_SYNI + 8000000)
#define WS_SS    (WS_SNS + 8000000)
#define WS_NEED  (WS_SS + 8000000)       // 32,131,072

__device__ __forceinline__ u16 f2bf(float f) {
    union { float f; u32 u; } v; v.f = f;
    u32 u = v.u;
    u32 lsb = (u >> 16) & 1u;
    u += 0x7fffu + lsb;            // RNE
    return (u16)(u >> 16);
}
__device__ __forceinline__ float bf2f(u16 b) {
    union { u32 u; float f; } v; v.u = ((u32)b) << 16; return v.f;
}
__device__ __forceinline__ void unpack8(uint4 u, float* x) {
    union { u32 u; float f; } c;
    c.u = u.x << 16;          x[0] = c.f;
    c.u = u.x & 0xffff0000u;  x[1] = c.f;
    c.u = u.y << 16;          x[2] = c.f;
    c.u = u.y & 0xffff0000u;  x[3] = c.f;
    c.u = u.z << 16;          x[4] = c.f;
    c.u = u.z & 0xffff0000u;  x[5] = c.f;
    c.u = u.w << 16;          x[6] = c.f;
    c.u = u.w & 0xffff0000u;  x[7] = c.f;
}
__device__ __forceinline__ float fast_tanh(float x) {
    x = fminf(fmaxf(x, -15.f), 15.f);
    float e = __expf(2.f * x);
    return 1.f - 2.f / (e + 1.f);
}
__device__ __forceinline__ float fast_sigmoid(float x) {
    x = fminf(fmaxf(x, -30.f), 30.f);
    return 1.f / (1.f + __expf(-x));
}

// ============================================================================
// k_lists: synapse->subunit assignment lists. One block.
// ============================================================================
__global__ __launch_bounds__(256) void k_lists(
    const float* __restrict__ Cse, const float* __restrict__ Csi,
    int* __restrict__ lists)
{
    __shared__ int easn[E_NO], iasn[I_NO];
    __shared__ int cnt[2 * SUB_NO], cur[2 * SUB_NO];
    const int tid = threadIdx.x;
    if (tid < 2 * SUB_NO) cnt[tid] = 0;
    __syncthreads();
    for (int j = tid; j < E_NO; j += 256) {
        int a = 0;
        for (int s = 0; s < SUB_NO; ++s)
            if (Cse[s * E_NO + j] > 0.5f) a = s;
        easn[j] = a;
        atomicAdd(&cnt[a], 1);
    }
    for (int j = tid; j < I_NO; j += 256) {
        int a = 0;
        for (int s = 0; s < SUB_NO; ++s)
            if (Csi[s * I_NO + j] > 0.5f) a = s;
        iasn[j] = a;
        atomicAdd(&cnt[SUB_NO + a], 1);
    }
    __syncthreads();
    if (tid == 0) {
        int aE = 0, aI = 0;
        for (int s = 0; s < SUB_NO; ++s) {
            lists[s] = aE;      cur[s] = aE;           aE += cnt[s];
            lists[21 + s] = aI; cur[SUB_NO + s] = aI;  aI += cnt[SUB_NO + s];
        }
        lists[20] = aE;
        lists[41] = aI;
    }
    __syncthreads();
    for (int j = tid; j < E_NO; j += 256) {
        int p = atomicAdd(&cur[easn[j]], 1);
        lists[42 + p] = j;
    }
    for (int j = tid; j < I_NO; j += 256) {
        int p = atomicAdd(&cur[SUB_NO + iasn[j]], 1);
        lists[442 + p] = j;
    }
}

// ============================================================================
// k_filters: 21 blocks. 0..19: subunit kernels + outF. 20: hist kernels.
// ============================================================================
__global__ __launch_bounds__(256) void k_filters(
    const float* __restrict__ Wns, const float* __restrict__ Tau,
    const float* __restrict__ Del, const float* __restrict__ Wsyns,
    const float* __restrict__ HwS, const float* __restrict__ HwNS,
    float4* __restrict__ k4, float2* __restrict__ hist2,
    float* __restrict__ outF)
{
    __shared__ float cb[N_BASIS * T_NO];
    const int tid = threadIdx.x;
    const int b = blockIdx.x;
    const float PI = 3.14159265358979323846f;

    for (int it = tid; it < N_BASIS * T_NO; it += 256) {
        int bb = it / T_NO, j = it - bb * T_NO;
        float phi = 1.57079632679489662f * (float)bb;
        float raw = 5.0f * logf((float)j + 1.0f);
        float v = 0.f;
        if (raw >= phi - PI && raw <= phi + PI) v = 0.5f * cosf(raw - phi) + 0.5f;
        cb[it] = v;
    }
    __syncthreads();

    if (b < 20) {
        const int s = b;
        if (tid < T_NO) {
            const int j = tid;
            float tau_e = Tau[s * 2 + 0]; tau_e *= tau_e;
            float tau_i = Tau[s * 2 + 1]; tau_i *= tau_i;
            float de = Del[s * 2 + 0], di = Del[s * 2 + 1];
            float we = Wns[s * 2 + 0]; we *= we;
            float wi = Wns[s * 2 + 1]; wi *= wi;
            float te = fmaxf((float)j - de, 0.f) / tau_e;
            float ti = fmaxf((float)j - di, 0.f) / tau_i;
            float eNs = te * expf(-te) * we;
            float iNs = -ti * expf(-ti) * wi;
            float eS = 0.f, iS = 0.f;
            for (int bb = 0; bb < N_BASIS; ++bb) {
                float w0 = Wsyns[(s * N_BASIS + bb) * 2 + 0];
                float w1 = Wsyns[(s * N_BASIS + bb) * 2 + 1];
                float c = cb[bb * T_NO + j];
                eS += w0 * w0 * c;
                iS -= w1 * w1 * c;
            }
            int it = s * T_NO + j;
            k4[it] = make_float4(eNs, iNs, eS, iS);
            outF[it]         = eNs;
            outF[4000 + it]  = iNs;
            outF[8000 + it]  = eS;
            outF[12000 + it] = iS;
        }
    } else {
        if (tid < T_NO) {
            const int j = tid;
            float hn = 0.f, hs = 0.f;
            for (int bb = 0; bb < N_BASIS; ++bb) {
                float c = cb[bb * T_NO + j];
                hn += HwNS[bb] * c;
                hs += HwS[bb] * c;
            }
            hist2[j] = make_float2(hn, hs);
            outF[16000 + j] = hn;
            outF[16200 + j] = hs;
        }
    }
}

// ============================================================================
// k_spikes (big path): spike sums -> bf16 synEb/synIb in ws. 16 t per block.
// LDS 34 KB -> 4 blocks/CU. Padded strides 404/104 f32; tasks grouped by s.
// ============================================================================
#define AR 16
__global__ __launch_bounds__(256) void k_spikes(
    const float* __restrict__ Se, const float* __restrict__ Si,
    const int* __restrict__ listsg,
    u16* __restrict__ synEb, u16* __restrict__ synIb)
{
    __shared__ __align__(16) float tE[AR * 404];
    __shared__ __align__(16) float tI[AR * 104];
    __shared__ int leo[21], lio[21];
    __shared__ u16 lei[E_NO], lii[I_NO];
    const int tid = threadIdx.x;
    const int t0 = blockIdx.x * AR;

    if (tid < 21) { leo[tid] = listsg[tid]; lio[tid] = listsg[21 + tid]; }
    for (int k = tid; k < E_NO; k += 256) lei[k] = (u16)listsg[42 + k];
    for (int k = tid; k < I_NO; k += 256) lii[k] = (u16)listsg[442 + k];

    const float4* Se4 = (const float4*)(Se + (size_t)t0 * E_NO);
    const float4* Si4 = (const float4*)(Si + (size_t)t0 * I_NO);
    for (int k = tid; k < AR * 100; k += 256) {
        int r = k / 100, c = k - r * 100;
        ((float4*)tE)[r * 101 + c] = Se4[k];
    }
    for (int k = tid; k < AR * 25; k += 256) {
        int r = k / 25, c = k - r * 25;
        ((float4*)tI)[r * 26 + c] = Si4[k];
    }
    __syncthreads();

    // E: 320 tasks, task -> (s = task>>4, r = task&15); lanes share s.
    for (int task = tid; task < AR * SUB_NO; task += 256) {
        int s = task >> 4, r = task & 15;
        int k0 = leo[s], k1 = leo[s + 1];
        const float* row = tE + r * 404;
        float a0 = 0.f, a1 = 0.f, a2 = 0.f, a3 = 0.f;
        int k = k0;
        for (; k + 4 <= k1; k += 4) {
            a0 += row[lei[k]];
            a1 += row[lei[k + 1]];
            a2 += row[lei[k + 2]];
            a3 += row[lei[k + 3]];
        }
        for (; k < k1; ++k) a0 += row[lei[k]];
        synEb[(size_t)s * T_DATA + t0 + r] = f2bf((a0 + a1) + (a2 + a3));
    }
    for (int task = tid; task < AR * SUB_NO; task += 256) {
        int s = task >> 4, r = task & 15;
        const float* row = tI + r * 104;
        float a = 0.f;
        for (int k = lio[s]; k < lio[s + 1]; ++k) a += row[lii[k]];
        synIb[(size_t)s * T_DATA + t0 + r] = f2bf(a);
    }
}

// ============================================================================
// k_conv (big path): depthwise conv, 4 subunits x 512 t per block.
// LDS 24.2 KB -> 6 blocks/CU. Wave = 1 subunit, M=8 outputs/thread.
// ============================================================================
#define TT 512
#define WROW 712
__global__ __launch_bounds__(256) void k_conv(
    const u16* __restrict__ synEb, const u16* __restrict__ synIb,
    const float4* __restrict__ k4g,
    u16* __restrict__ synNSb, u16* __restrict__ synSb)
{
    __shared__ __align__(16) u16 wE[4 * WROW];        // 5696 B
    __shared__ __align__(16) u16 wI[4 * WROW];        // 5696 B
    __shared__ __align__(16) float4 k4l[4 * T_NO];    // 12800 B
    const int tid = threadIdx.x;
    const int t0 = blockIdx.x * TT;
    const int g  = blockIdx.y;
    const int W0 = t0 - 200;

    // window load: 4 rows x 89 uint4 x 2 arrays = 712 chunks
    for (int q = tid; q < 712; q += 256) {
        int arr = (q >= 356) ? 1 : 0;
        int qq = q - arr * 356;
        int row = qq / 89, c = qq - row * 89;
        int s = g * 4 + row;
        const u16* src = (arr ? synIb : synEb) + (size_t)s * T_DATA;
        u16* dst = (arr ? wI : wE) + row * WROW + c * 8;
        int gg = W0 + c * 8;
        if (gg >= 0 && gg + 8 <= T_DATA) {
            *(uint4*)dst = *(const uint4*)(src + gg);
        } else {
            for (int e = 0; e < 8; ++e) {
                int t = gg + e;
                dst[e] = (t >= 0 && t < T_DATA) ? src[t] : (u16)0;
            }
        }
    }
    for (int q = tid; q < 800; q += 256) {
        int su = q / 200, j = q - su * 200;
        k4l[q] = k4g[(g * 4 + su) * T_NO + j];
    }
    __syncthreads();

    const int wv = tid >> 6;         // wave -> subunit row (wave-uniform)
    const int slot = tid & 63;
    const int bT = slot * 8;
    const int s = g * 4 + wv;
    const u16* rowE = wE + wv * WROW;
    const u16* rowI = wI + wv * WROW;

    float aN[8], aS2[8];
#pragma unroll
    for (int m = 0; m < 8; ++m) { aN[m] = 0.f; aS2[m] = 0.f; }

#pragma unroll 1
    for (int jj = 0; jj <= 192; jj += 8) {
        const int p = bT + 192 - jj;             // mult of 8 -> 16B aligned
        float xe[16], xi[16];
        uint4 eA = *(const uint4*)(rowE + p);
        uint4 eB = *(const uint4*)(rowE + p + 8);
        uint4 iA = *(const uint4*)(rowI + p);
        uint4 iB = *(const uint4*)(rowI + p + 8);
        unpack8(eA, xe); unpack8(eB, xe + 8);
        unpack8(iA, xi); unpack8(iB, xi + 8);
#pragma unroll
        for (int k = 0; k < 8; ++k) {
            float4 kk = k4l[wv * T_NO + jj + k];  // wave-uniform broadcast
#pragma unroll
            for (int m = 0; m < 8; ++m) {
                float e = xe[m + 8 - k];
                float ii = xi[m + 8 - k];
                aN[m]  = fmaf(e, kk.x, fmaf(ii, kk.y, aN[m]));
                aS2[m] = fmaf(e, kk.z, fmaf(ii, kk.w, aS2[m]));
            }
        }
    }

    // store 8 bf16 per array as uint4
    const int t = t0 + bT;
    u32 w0 = (u32)f2bf(aN[0]) | ((u32)f2bf(aN[1]) << 16);
    u32 w1 = (u32)f2bf(aN[2]) | ((u32)f2bf(aN[3]) << 16);
    u32 w2 = (u32)f2bf(aN[4]) | ((u32)f2bf(aN[5]) << 16);
    u32 w3 = (u32)f2bf(aN[6]) | ((u32)f2bf(aN[7]) << 16);
    u32 v0 = (u32)f2bf(aS2[0]) | ((u32)f2bf(aS2[1]) << 16);
    u32 v1 = (u32)f2bf(aS2[2]) | ((u32)f2bf(aS2[3]) << 16);
    u32 v2 = (u32)f2bf(aS2[4]) | ((u32)f2bf(aS2[5]) << 16);
    u32 v3 = (u32)f2bf(aS2[6]) | ((u32)f2bf(aS2[7]) << 16);
    if (t + 8 <= T_DATA) {
        *(uint4*)(synNSb + (size_t)s * T_DATA + t) = make_uint4(w0, w1, w2, w3);
        *(uint4*)(synSb  + (size_t)s * T_DATA + t) = make_uint4(v0, v1, v2, v3);
    } else if (t < T_DATA) {
        u16 nv[8] = { f2bf(aN[0]), f2bf(aN[1]), f2bf(aN[2]), f2bf(aN[3]),
                      f2bf(aN[4]), f2bf(aN[5]), f2bf(aN[6]), f2bf(aN[7]) };
        u16 sv[8] = { f2bf(aS2[0]), f2bf(aS2[1]), f2bf(aS2[2]), f2bf(aS2[3]),
                      f2bf(aS2[4]), f2bf(aS2[5]), f2bf(aS2[6]), f2bf(aS2[7]) };
        for (int m = 0; m < 8 && t + m < T_DATA; ++m) {
            synNSb[(size_t)s * T_DATA + t + m] = nv[m];
            synSb[(size_t)s * T_DATA + t + m] = sv[m];
        }
    }
}

// ============================================================================
// k_tree (big path): hist + tree + f32 outputs. 256 t per block, 1 t/thread.
// LDS 27.3 KB -> 5 blocks/CU.
// ============================================================================
#define CT 256
__global__ __launch_bounds__(256) void k_tree(
    const u16* __restrict__ synNSb, const u16* __restrict__ synSb,
    const float* __restrict__ Z, const float2* __restrict__ hist2g,
    const int* __restrict__ Cden,
    const float* __restrict__ WsubNS, const float* __restrict__ WsubS,
    const float* __restrict__ Vo, const float* __restrict__ ThNS,
    const float* __restrict__ ThS,
    float* __restrict__ outV, float* __restrict__ outZ)
{
    __shared__ __align__(16) u16 lNS[SUB_NO * CT];    // 10240 B
    __shared__ __align__(16) u16 lS[SUB_NO * CT];     // 10240 B
    __shared__ float Zw[456];
    __shared__ float2 hl[T_NO];
    __shared__ float AS[SUB_NO][SUB_NO], AN[SUB_NO][SUB_NO];
    __shared__ float ths[SUB_NO], thn[SUB_NO];
    __shared__ float wn20s, vos;
    const int tid = threadIdx.x;
    const int t0 = blockIdx.x * CT;

    // load syn rows: 20 rows x 32 uint4 x 2 arrays
    for (int q = tid; q < 1280; q += 256) {
        int arr = (q >= 640) ? 1 : 0;
        int qq = q - arr * 640;
        int row = qq >> 5, c = qq & 31;
        const u16* src = (arr ? synSb : synNSb) + (size_t)row * T_DATA;
        u16* dst = (arr ? lS : lNS) + row * CT + c * 8;
        int gg = t0 + c * 8;
        if (gg + 8 <= T_DATA) {
            *(uint4*)dst = *(const uint4*)(src + gg);
        } else {
            for (int e = 0; e < 8; ++e) {
                int t = gg + e;
                dst[e] = (t < T_DATA) ? src[t] : (u16)0;
            }
        }
    }
    for (int k = tid; k < 456; k += 256) {
        int t = t0 - 200 + k;
        Zw[k] = (t >= 0 && t < T_DATA) ? Z[t] : 0.f;
    }
    if (tid < T_NO) hl[tid] = hist2g[tid];
    for (int k = tid; k < SUB_NO * SUB_NO; k += 256) {
        int idx = k / SUB_NO, c = k - idx * SUB_NO;
        float m = (float)Cden[k];
        float wsv = WsubS[c];
        float wnv = WsubNS[c];
        AS[idx][c] = m * wsv * wsv;
        AN[idx][c] = m * wnv * wnv;
    }
    if (tid < SUB_NO) { ths[tid] = ThS[tid]; thn[tid] = ThNS[tid]; }
    if (tid == 0) {
        float w = WsubNS[0];
        wn20s = w * w;
        vos = Vo[0];
    }
    __syncthreads();

    const int t = t0 + tid;
    float hn = 0.f, hs = 0.f;
    for (int j = 0; j < T_NO; ++j) {
        float2 h = hl[j];
        float z = Zw[tid + 199 - j];     // Z[t-1-j]
        hn = fmaf(h.x, z, hn);
        hs = fmaf(h.y, z, hs);
    }

    float vs[SUB_NO], vn[SUB_NO];
#pragma unroll
    for (int c = 0; c < SUB_NO; ++c) { vs[c] = 0.f; vn[c] = 0.f; }
#pragma unroll
    for (int idx = SUB_NO - 1; idx >= 1; --idx) {
        float cs = 0.f, cn = 0.f;
#pragma unroll
        for (int c = 0; c < SUB_NO; ++c) {
            cs = fmaf(AS[idx][c], vs[c], cs);
            cn = fmaf(AN[idx][c], vn[c], cn);
        }
        float synS_v = bf2f(lS[idx * CT + tid]);
        float synN_v = bf2f(lNS[idx * CT + tid]);
        vs[idx] = fast_tanh(synS_v + cs + ths[idx]);
        vn[idx] = fast_tanh(synN_v + cn + thn[idx]);
    }
    float cs0 = 0.f, cn0 = 0.f;
#pragma unroll
    for (int c = 0; c < SUB_NO; ++c) {
        cs0 = fmaf(AS[0][c], vs[c], cs0);
        cn0 = fmaf(AN[0][c], vn[c], cn0);
    }
    float s0  = fast_sigmoid(hs + bf2f(lS[tid]) + cs0 + ths[0]);
    float ns0 = fast_tanh(hn + bf2f(lNS[tid]) + cn0 + thn[0]);

    if (t < T_DATA) {
        outV[t] = ns0 * wn20s + vos;
        outZ[t] = s0;
    }
}

// ============================================================================
// k_fused (fallback, R8-proven): used only when ws_size < WS_NEED.
// ============================================================================
__global__ __launch_bounds__(256) void k_fused(
    const float* __restrict__ Se, const float* __restrict__ Si,
    const float* __restrict__ Z,
    const float4* __restrict__ k4g, const float2* __restrict__ hist2g,
    const int* __restrict__ listsg,
    const int* __restrict__ Cden,
    const float* __restrict__ WsubNS, const float* __restrict__ WsubS,
    const float* __restrict__ Vo, const float* __restrict__ ThNS,
    const float* __restrict__ ThS,
    float* __restrict__ outV, float* __restrict__ outZ)
{
    __shared__ __align__(16) u16 sE[SUB_NO * WROW];
    __shared__ __align__(16) u16 sI[SUB_NO * WROW];
    __shared__ __align__(16) float scr[4032];
    __shared__ float AS[SUB_NO][SUB_NO], AN[SUB_NO][SUB_NO];
    __shared__ float ths[SUB_NO], thn[SUB_NO];
    __shared__ int leo[21], lio[21];
    __shared__ u16 lei[E_NO], lii[I_NO];
    __shared__ float wn20s, vos;
    const int tid = threadIdx.x;
    const int t0 = blockIdx.x * TT;
    const int W0 = t0 - 200;

    if (tid < 21) { leo[tid] = listsg[tid]; lio[tid] = listsg[21 + tid]; }
    for (int k = tid; k < E_NO; k += 256) lei[k] = (u16)listsg[42 + k];
    for (int k = tid; k < I_NO; k += 256) lii[k] = (u16)listsg[442 + k];
    for (int k = tid; k < SUB_NO * SUB_NO; k += 256) {
        int idx = k / SUB_NO, c = k - idx * SUB_NO;
        float m = (float)Cden[k];
        float wsv = WsubS[c];
        float wnv = WsubNS[c];
        AS[idx][c] = m * wsv * wsv;
        AN[idx][c] = m * wnv * wnv;
    }
    if (tid < SUB_NO) { ths[tid] = ThS[tid]; thn[tid] = ThNS[tid]; }
    if (tid == 0) {
        float w = WsubNS[0];
        wn20s = w * w;
        vos = Vo[0];
    }

    const float4* Se4 = (const float4*)Se;
    const float4* Si4 = (const float4*)Si;
    float4* scr4 = (float4*)scr;
    float4 pre[4];

#define LOAD_TILE(IT)                                                        \
    {                                                                        \
        _Pragma("unroll")                                                    \
        for (int q = 0; q < 4; ++q) {                                        \
            int k = tid + q * 256;                                           \
            float4 v = make_float4(0.f, 0.f, 0.f, 0.f);                      \
            if (k < 800) {                                                   \
                int r = k / 100, c = k - r * 100;                            \
                int t = W0 + (IT) * 8 + r;                                   \
                if (t >= 0 && t < T_DATA) v = Se4[t * 100 + c];              \
            } else if (k < 1000) {                                           \
                int kk = k - 800;                                            \
                int r = kk / 25, c = kk - r * 25;                            \
                int t = W0 + (IT) * 8 + r;                                   \
                if (t >= 0 && t < T_DATA) v = Si4[t * 25 + c];               \
            }                                                                \
            pre[q] = v;                                                      \
        }                                                                    \
    }

#define STORE_TILE()                                                         \
    {                                                                        \
        _Pragma("unroll")                                                    \
        for (int q = 0; q < 4; ++q) {                                        \
            int k = tid + q * 256;                                           \
            if (k < 800) {                                                   \
                scr4[k] = pre[q];                                            \
            } else if (k < 1000) {                                           \
                int kk = k - 800;                                            \
                int r = kk / 25, c = kk - r * 25;                            \
                scr4[800 + r * 26 + c] = pre[q];                             \
            }                                                                \
        }                                                                    \
    }

#define GATHER(IT)                                                           \
    {                                                                        \
        for (int task = tid; task < 320; task += 256) {                      \
            if (task < 160) {                                                \
                int r = task / 20, s = task - r * 20;                        \
                int k0 = leo[s], k1 = leo[s + 1];                            \
                const int bb = r * 400;                                      \
                float a0 = 0.f, a1 = 0.f, a2 = 0.f, a3 = 0.f;                \
                int k = k0;                                                  \
                for (; k + 4 <= k1; k += 4) {                                \
                    a0 += scr[bb + lei[k]];                                  \
                    a1 += scr[bb + lei[k + 1]];                              \
                    a2 += scr[bb + lei[k + 2]];                              \
                    a3 += scr[bb + lei[k + 3]];                              \
                }                                                            \
                for (; k < k1; ++k) a0 += scr[bb + lei[k]];                  \
                sE[s * WROW + (IT) * 8 + r] = f2bf((a0 + a1) + (a2 + a3));   \
            } else {                                                         \
                int tk = task - 160;                                         \
                int r = tk / 20, s = tk - r * 20;                            \
                int k0 = lio[s], k1 = lio[s + 1];                            \
                const int bb = 3200 + r * 104;                               \
                float a0 = 0.f;                                              \
                for (int k = k0; k < k1; ++k) a0 += scr[bb + lii[k]];        \
                sI[s * WROW + (IT) * 8 + r] = f2bf(a0);                      \
            }                                                                \
        }                                                                    \
    }

    LOAD_TILE(0);
    STORE_TILE();
    __syncthreads();
#pragma unroll 1
    for (int it = 1; it < 89; ++it) {
        LOAD_TILE(it);
        GATHER(it - 1);
        __syncthreads();
        STORE_TILE();
        __syncthreads();
    }
    GATHER(88);
    __syncthreads();

    for (int k = tid; k < WROW; k += 256) {
        int t = W0 + k;
        scr[k] = (t >= 0 && t < T_DATA) ? Z[t] : 0.f;
    }
    {
        float2* hl = (float2*)(scr + WROW);
        for (int k = tid; k < T_NO; k += 256) hl[k] = hist2g[k];
    }
    __syncthreads();
    float hn0 = 0.f, hs0 = 0.f, hn1 = 0.f, hs1 = 0.f;
    {
        const float2* hl = (const float2*)(scr + WROW);
        const int i0 = tid * 2;
        for (int j = 0; j < T_NO; ++j) {
            float2 h = hl[j];
            float za = scr[i0 + 199 - j];
            float zb = scr[i0 + 200 - j];
            hn0 = fmaf(h.x, za, hn0); hs0 = fmaf(h.y, za, hs0);
            hn1 = fmaf(h.x, zb, hn1); hs1 = fmaf(h.y, zb, hs1);
        }
    }
    __syncthreads();

    const int wv = tid >> 6;
    const int slot = tid & 63;
    const int bT = slot * 8;
    float4* k4c = (float4*)scr;

#pragma unroll 1
    for (int g = 0; g < 5; ++g) {
        for (int q = tid; q < 800; q += 256) {
            int su = q / 200, j = q - su * 200;
            k4c[q] = k4g[(g * 4 + su) * T_NO + j];
        }
        __syncthreads();

        const int s = g * 4 + wv;
        const u16* rowE = sE + s * WROW;
        const u16* rowI = sI + s * WROW;
        float aN[8], aS2[8];
#pragma unroll
        for (int m = 0; m < 8; ++m) { aN[m] = 0.f; aS2[m] = 0.f; }

#pragma unroll 1
        for (int jj = 0; jj <= 192; jj += 8) {
            const int p = bT + 192 - jj;
            float xe[16], xi[16];
            uint4 eA = *(const uint4*)(rowE + p);
            uint4 eB = *(const uint4*)(rowE + p + 8);
            uint4 iA = *(const uint4*)(rowI + p);
            uint4 iB = *(const uint4*)(rowI + p + 8);
            unpack8(eA, xe); unpack8(eB, xe + 8);
            unpack8(iA, xi); unpack8(iB, xi + 8);
#pragma unroll
            for (int k = 0; k < 8; ++k) {
                float4 kk = k4c[wv * 200 + jj + k];
#pragma unroll
                for (int m = 0; m < 8; ++m) {
                    float e = xe[m + 8 - k];
                    float ii = xi[m + 8 - k];
                    aN[m]  = fmaf(e, kk.x, fmaf(ii, kk.y, aN[m]));
                    aS2[m] = fmaf(e, kk.z, fmaf(ii, kk.w, aS2[m]));
                }
            }
        }
        __syncthreads();
        {
            u32 w0 = (u32)f2bf(aN[0]) | ((u32)f2bf(aN[1]) << 16);
            u32 w1 = (u32)f2bf(aN[2]) | ((u32)f2bf(aN[3]) << 16);
            u32 w2 = (u32)f2bf(aN[4]) | ((u32)f2bf(aN[5]) << 16);
            u32 w3 = (u32)f2bf(aN[6]) | ((u32)f2bf(aN[7]) << 16);
            *(uint4*)(sE + s * WROW + bT) = make_uint4(w0, w1, w2, w3);
            u32 v0 = (u32)f2bf(aS2[0]) | ((u32)f2bf(aS2[1]) << 16);
            u32 v1 = (u32)f2bf(aS2[2]) | ((u32)f2bf(aS2[3]) << 16);
            u32 v2 = (u32)f2bf(aS2[4]) | ((u32)f2bf(aS2[5]) << 16);
            u32 v3 = (u32)f2bf(aS2[6]) | ((u32)f2bf(aS2[7]) << 16);
            *(uint4*)(sI + s * WROW + bT) = make_uint4(v0, v1, v2, v3);
        }
    }
    __syncthreads();

#pragma unroll 1
    for (int m = 0; m < 2; ++m) {
        const int i = tid * 2 + m;
        const int t = t0 + i;
        const float hfn = (m == 0) ? hn0 : hn1;
        const float hfs = (m == 0) ? hs0 : hs1;

        float vs[SUB_NO], vn[SUB_NO];
#pragma unroll
        for (int c = 0; c < SUB_NO; ++c) { vs[c] = 0.f; vn[c] = 0.f; }
#pragma unroll
        for (int idx = SUB_NO - 1; idx >= 1; --idx) {
            float cs = 0.f, cn = 0.f;
#pragma unroll
            for (int c = 0; c < SUB_NO; ++c) {
                cs = fmaf(AS[idx][c], vs[c], cs);
                cn = fmaf(AN[idx][c], vn[c], cn);
            }
            float synS_v = bf2f(sI[idx * WROW + i]);
            float synN_v = bf2f(sE[idx * WROW + i]);
            vs[idx] = fast_tanh(synS_v + cs + ths[idx]);
            vn[idx] = fast_tanh(synN_v + cn + thn[idx]);
        }
        float cs0 = 0.f, cn0 = 0.f;
#pragma unroll
        for (int c = 0; c < SUB_NO; ++c) {
            cs0 = fmaf(AS[0][c], vs[c], cs0);
            cn0 = fmaf(AN[0][c], vn[c], cn0);
        }
        float s0  = fast_sigmoid(hfs + bf2f(sI[i]) + cs0 + ths[0]);
        float ns0 = fast_tanh(hfn + bf2f(sE[i]) + cn0 + thn[0]);

        if (t < T_DATA) {
            outV[t] = ns0 * wn20s + vos;
            outZ[t] = s0;
        }
    }
}

// ============================================================================
extern "C" void kernel_launch(void* const* d_in, const int* in_sizes, int n_in,
                              void* d_out, int out_size, void* d_ws, size_t ws_size,
                              hipStream_t stream)
{
    const float* Se    = (const float*)d_in[0];
    const float* Si    = (const float*)d_in[1];
    const float* Z     = (const float*)d_in[2];
    const int*   Cden  = (const int*)d_in[3];
    const float* Cse   = (const float*)d_in[4];
    const float* Csi   = (const float*)d_in[5];
    const float* Wns   = (const float*)d_in[6];
    const float* Tau   = (const float*)d_in[7];
    const float* Del   = (const float*)d_in[8];
    const float* Wsyns = (const float*)d_in[9];
    const float* WsubNS= (const float*)d_in[10];
    const float* WsubS = (const float*)d_in[11];
    const float* Vo    = (const float*)d_in[12];
    const float* ThNS  = (const float*)d_in[13];
    const float* ThS   = (const float*)d_in[14];
    const float* HwS   = (const float*)d_in[15];
    const float* HwNS  = (const float*)d_in[16];

    char* ws = (char*)d_ws;
    float4* k4    = (float4*)(ws + WS_K4);
    float2* hist2 = (float2*)(ws + WS_HIST2);
    int*    lists = (int*)(ws + WS_LISTS);

    float* outV = (float*)d_out;
    float* outZ = outV + T_DATA;
    float* outF = outV + 2 * T_DATA;

    k_lists<<<1, 256, 0, stream>>>(Cse, Csi, lists);
    k_filters<<<21, 256, 0, stream>>>(Wns, Tau, Del, Wsyns, HwS, HwNS,
                                      k4, hist2, outF);

    if (ws_size >= (size_t)WS_NEED) {
        u16* synEb  = (u16*)(ws + WS_SYNE);
        u16* synIb  = (u16*)(ws + WS_SYNI);
        u16* synNSb = (u16*)(ws + WS_SNS);
        u16* synSb  = (u16*)(ws + WS_SS);
        k_spikes<<<T_DATA / AR, 256, 0, stream>>>(Se, Si, lists, synEb, synIb);
        dim3 gc((T_DATA + TT - 1) / TT, 5);
        k_conv<<<gc, 256, 0, stream>>>(synEb, synIb, k4, synNSb, synSb);
        k_tree<<<(T_DATA + CT - 1) / CT, 256, 0, stream>>>(
            synNSb, synSb, Z, hist2, Cden, WsubNS, WsubS, Vo, ThNS, ThS,
            outV, outZ);
    } else {
        k_fused<<<(T_DATA + TT - 1) / TT, 256, 0, stream>>>(
            Se, Si, Z, k4, hist2, lists, Cden, WsubNS, WsubS, Vo, ThNS, ThS,
            outV, outZ);
    }
}